// Round 17
// baseline (125.012 us; speedup 1.0000x reference)
//
#include <hip/hip_runtime.h>

// SmearImages — round 17: r15 + 512-thread blocks (8 waves), 4 points/thread.
// History: r6 84us; r11 (LDS-transpose stores) 48us; r14 (+camera->XCD pinning)
// 52us FETCH 23.8MB; r16 (+float2 corner-pair gathers, 12->6 VMEM/pt) 42.2us,
// VGPR 48, occupancy 26.8% — latency-bound, occupancy capped by grid shape
// (1024 blk x 4 waves = 16 waves/CU = 50% of slots). r17 doubles waves/block
// (512 thr), halves points/thread (4 iz), grid unchanged -> 8192 waves = 100%
// of slots. Store structure preserved: block still owns full 128B sectors.
#define Bc   2
#define IPc  4
#define Cc   3
#define Hc   480
#define Wc   640
#define Nc   (64 * 64 * 64)
#define CHo  8
#define LDSP 36   // [64][36] floats: rows 144B (16B-aligned); measured 0 bank conflicts

typedef float f32x4 __attribute__((ext_vector_type(4)));
typedef float f32x2_a4 __attribute__((ext_vector_type(2), aligned(4)));  // 4B-aligned pair load

// stage one channel: regs -> LDS tile [ix][iz_local] -> transposed NT store
// 512 threads: thread writes f32x4 at [ix][wv*4]; store phase: izs=t&31,
// ixr=t>>5 (0..15), s in 0..3 -> ixs = s*16+ixr. Wave = rows (2w,2w+1): two
// full 128B runs per store instruction.
#define STAGE(CH, ARR)                                                                 \
  do {                                                                                 \
    f32x4 w0 = { (ARR)[0], (ARR)[1], (ARR)[2], (ARR)[3] };                             \
    *reinterpret_cast<f32x4*>(&lds[ix * LDSP + wv * 4]) = w0;                          \
    __syncthreads();                                                                   \
    float* __restrict__ op = out + ((size_t)(bip * CHo + (CH))) * Nc + iy * 64 + izc * 32; \
    _Pragma("unroll")                                                                  \
    for (int s = 0; s < 4; ++s) {                                                      \
      const int ixs = s * 16 + (t >> 5);                                               \
      const int izs = t & 31;                                                          \
      __builtin_nontemporal_store(lds[ixs * LDSP + izs], op + ixs * 4096 + izs);       \
    }                                                                                  \
    __syncthreads();                                                                   \
  } while (0)

__global__ __launch_bounds__(512) void smear_images_kernel(
    const float* __restrict__ images,
    const float* __restrict__ trans,
    const float* __restrict__ tcw,
    const float* __restrict__ coords,
    float* __restrict__ out)
{
    __shared__ float lds[64 * LDSP];

    const int t   = threadIdx.x;
    const int ix  = t & 63;          // lane = ix (outermost voxel axis)
    const int wv  = t >> 6;          // wave 0..7 -> 4-iz sub-chunk
    const int bip = blockIdx.x;      // camera FASTEST -> linear id = bip + 8*gx -> XCD = bip
    const int gx  = blockIdx.y;      // 0..127
    const int iy  = gx >> 1;
    const int izc = gx & 1;          // 32-iz half
    const int b   = bip >> 2;

    // ---- per-camera parameters (wave-uniform -> scalar loads) ----
    const float* __restrict__ M = trans + bip * 12;
    const float m00 = M[0],  m01 = M[1],  m02 = M[2],  m03 = M[3];
    const float m10 = M[4],  m11 = M[5],  m12 = M[6],  m13 = M[7];
    const float m20 = M[8],  m21 = M[9],  m22 = M[10], m23 = M[11];

    const float* __restrict__ T = tcw + bip * 16;
    const float r00 = T[0], r01 = T[1], r02 = T[2],  t0 = T[3];
    const float r10 = T[4], r11 = T[5], r12 = T[6],  t1 = T[7];
    const float r20 = T[8], r21 = T[9], r22 = T[10], t2 = T[11];
    const float ccx = -(r00 * t0 + r10 * t1 + r20 * t2);
    const float ccy = -(r01 * t0 + r11 * t1 + r21 * t2);
    const float ccz = -(r02 * t0 + r12 * t1 + r22 * t2);

    const size_t img_base = (size_t)bip * Cc * Hc * Wc;
    const size_t cb       = (size_t)b * 3 * Nc;
    const int    n0       = ix * 4096 + iy * 64 + izc * 32 + wv * 4;  // 4 consecutive n

    // ---- coords (meshgrid): px=f(ix), py=f(iy), pz = 4 contiguous floats ----
    const float px = coords[cb + n0];
    const float py = coords[cb + (size_t)Nc + n0];
    const f32x4 pzv = *reinterpret_cast<const f32x4*>(coords + cb + 2 * (size_t)Nc + n0);

    const float h0xy = m00 * px + m01 * py + m03;
    const float h1xy = m10 * px + m11 * py + m13;
    const float h2xy = m20 * px + m21 * py + m23;
    const float dxc  = px - ccx;
    const float dyc  = py - ccy;

    float rgb0[4], rgb1[4], rgb2[4], dep[4], vld[4], inv_[4], tmp[4];

    #pragma unroll
    for (int j = 0; j < 4; ++j) {
        const float pz = pzv[j];

        const float h0 = h0xy + m02 * pz;
        const float h1 = h1xy + m12 * pz;
        const float h2 = h2xy + m22 * pz;

        const float depth = h2;
        const float safe  = (fabsf(depth) > 1e-8f) ? depth : 1e-8f;
        const float u = h0 / safe;
        const float v = h1 / safe;

        const float valid = (depth > 0.0f && u >= 0.0f && u <= (float)(Wc - 1) &&
                             v >= 0.0f && v <= (float)(Hc - 1)) ? 1.0f : 0.0f;

        const float x0f = floorf(u);
        const float y0f = floorf(v);
        const float wx  = u - x0f;
        const float wy  = v - y0f;
        const int   x0  = (int)x0f;
        const int   y0  = (int)y0f;
        const int   x1  = x0 + 1;
        const int   y1  = y0 + 1;

        const float w00 = (1.0f - wx) * (1.0f - wy);
        const float w10 = wx * (1.0f - wy);
        const float w01 = (1.0f - wx) * wy;
        const float w11 = wx * wy;

        const bool ibx0 = (x0 >= 0) & (x0 < Wc);
        const bool ibx1 = (x1 >= 0) & (x1 < Wc);
        const bool iby0 = (y0 >= 0) & (y0 < Hc);
        const bool iby1 = (y1 >= 0) & (y1 < Hc);

        const int cx0 = min(max(x0, 0), Wc - 1);
        const int cx1 = min(max(x1, 0), Wc - 1);
        const int cy0 = min(max(y0, 0), Hc - 1);
        const int cy1 = min(max(y1, 0), Hc - 1);

        // corner-pair base: pair[0]=img[xb], pair[1]=img[xb+1]; cx0,cx1 in {xb,xb+1}
        const int  xb   = min(cx0, Wc - 2);
        const bool s0   = (cx0 != xb);   // select for corner x0
        const bool s1   = (cx1 != xb);   // select for corner x1
        const int  row0 = cy0 * Wc + xb;
        const int  row1 = cy1 * Wc + xb;

        #pragma unroll
        for (int c = 0; c < Cc; ++c) {
            const float* __restrict__ img = images + img_base + (size_t)c * (Hc * Wc);
            const f32x2_a4 p0 = *reinterpret_cast<const f32x2_a4*>(img + row0);
            const f32x2_a4 p1 = *reinterpret_cast<const f32x2_a4*>(img + row1);
            const float v00 = (ibx0 & iby0) ? (s0 ? p0.y : p0.x) : 0.0f;
            const float v10 = (ibx1 & iby0) ? (s1 ? p0.y : p0.x) : 0.0f;
            const float v01 = (ibx0 & iby1) ? (s0 ? p1.y : p1.x) : 0.0f;
            const float v11 = (ibx1 & iby1) ? (s1 ? p1.y : p1.x) : 0.0f;
            const float sres = v00 * w00 + v10 * w10 + v01 * w01 + v11 * w11;
            if (c == 0) rgb0[j] = sres;
            else if (c == 1) rgb1[j] = sres;
            else rgb2[j] = sres;
        }

        dep[j] = depth;
        vld[j] = valid;

        const float dz = pz - ccz;
        const float nrm = sqrtf(dxc * dxc + dyc * dyc + dz * dz);
        inv_[j] = 1.0f / fmaxf(nrm, 1e-8f);
    }

    STAGE(0, rgb0);
    STAGE(1, rgb1);
    STAGE(2, rgb2);
    STAGE(3, dep);
    STAGE(4, vld);

    #pragma unroll
    for (int j = 0; j < 4; ++j) tmp[j] = dxc * inv_[j];
    STAGE(5, tmp);
    #pragma unroll
    for (int j = 0; j < 4; ++j) tmp[j] = dyc * inv_[j];
    STAGE(6, tmp);
    #pragma unroll
    for (int j = 0; j < 4; ++j) tmp[j] = (pzv[j] - ccz) * inv_[j];
    STAGE(7, tmp);
}

extern "C" void kernel_launch(void* const* d_in, const int* in_sizes, int n_in,
                              void* d_out, int out_size, void* d_ws, size_t ws_size,
                              hipStream_t stream) {
    const float* images = (const float*)d_in[0];
    const float* trans  = (const float*)d_in[1];
    const float* tcw    = (const float*)d_in[2];
    const float* coords = (const float*)d_in[3];
    float* out = (float*)d_out;

    dim3 grid(Bc * IPc, 128);   // camera fastest: linear id = bip + 8*gx -> XCD = bip
    dim3 block(512);            // 8 waves/block: 1024 blk x 8 = 8192 waves = 100% slots
    smear_images_kernel<<<grid, block, 0, stream>>>(images, trans, tcw, coords, out);
}

// Round 18
// 116.469 us; speedup vs baseline: 1.0733x; 1.0733x over previous
//
#include <hip/hip_runtime.h>

// SmearImages — round 18: single-barrier structure (per-channel LDS regions).
// History: r6 84us; r11 LDS-transpose stores 48us; r14 camera->XCD pin 52us FETCH 24MB;
// r16 float2 pair-gathers 42.2us (VGPR 48!); r17 512-thr occupancy 37%: 48us (WORSE).
// Diagnosis: VGPR=48 < 56 live result floats => compiler sank each channel's gathers
// into its STAGE phase (LDS buffer reuse forces it) => 8-phase barrier convoy with
// serially exposed gather latency; occupancy was never the limit.
// r18: 8 per-channel LDS tiles (73.7KB, 2 blocks/CU), results drain to LDS as
// computed, ONE barrier, then a barrier-free store phase. All 48 gathers/thread
// can be in flight at once.
#define Bc   2
#define IPc  4
#define Cc   3
#define Hc   480
#define Wc   640
#define Nc   (64 * 64 * 64)
#define CHo  8
#define LDSP 36                    // row stride (floats): 144B, 16B-aligned
#define CHSZ (64 * LDSP)           // 2304 floats per channel tile

typedef float f32x4 __attribute__((ext_vector_type(4)));
typedef float f32x2_a4 __attribute__((ext_vector_type(2), aligned(4)));  // 4B-aligned pair load

__global__ __launch_bounds__(256) void smear_images_kernel(
    const float* __restrict__ images,
    const float* __restrict__ trans,
    const float* __restrict__ tcw,
    const float* __restrict__ coords,
    float* __restrict__ out)
{
    __shared__ float lds[CHo * CHSZ];   // 73728 B -> 2 blocks/CU

    const int t   = threadIdx.x;
    const int ix  = t & 63;          // lane = ix (outermost voxel axis)
    const int wv  = t >> 6;          // wave 0..3 -> 8-iz sub-chunk
    const int bip = blockIdx.x;      // camera FASTEST -> linear id = bip + 8*gx -> XCD = bip
    const int gx  = blockIdx.y;      // 0..127
    const int iy  = gx >> 1;
    const int izc = gx & 1;          // 32-iz half
    const int b   = bip >> 2;

    // ---- per-camera parameters (wave-uniform -> scalar loads) ----
    const float* __restrict__ M = trans + bip * 12;
    const float m00 = M[0],  m01 = M[1],  m02 = M[2],  m03 = M[3];
    const float m10 = M[4],  m11 = M[5],  m12 = M[6],  m13 = M[7];
    const float m20 = M[8],  m21 = M[9],  m22 = M[10], m23 = M[11];

    const float* __restrict__ T = tcw + bip * 16;
    const float r00 = T[0], r01 = T[1], r02 = T[2],  t0 = T[3];
    const float r10 = T[4], r11 = T[5], r12 = T[6],  t1 = T[7];
    const float r20 = T[8], r21 = T[9], r22 = T[10], t2 = T[11];
    const float ccx = -(r00 * t0 + r10 * t1 + r20 * t2);
    const float ccy = -(r01 * t0 + r11 * t1 + r21 * t2);
    const float ccz = -(r02 * t0 + r12 * t1 + r22 * t2);

    const size_t img_base = (size_t)bip * Cc * Hc * Wc;
    const size_t cb       = (size_t)b * 3 * Nc;
    const int    n0       = ix * 4096 + iy * 64 + izc * 32 + wv * 8;  // 8 consecutive n

    // ---- coords (meshgrid): px=f(ix), py=f(iy), pz = 8 contiguous floats ----
    const float px = coords[cb + n0];
    const float py = coords[cb + (size_t)Nc + n0];
    const f32x4 pza = *reinterpret_cast<const f32x4*>(coords + cb + 2 * (size_t)Nc + n0);
    const f32x4 pzb = *reinterpret_cast<const f32x4*>(coords + cb + 2 * (size_t)Nc + n0 + 4);

    const float h0xy = m00 * px + m01 * py + m03;
    const float h1xy = m10 * px + m11 * py + m13;
    const float h2xy = m20 * px + m21 * py + m23;
    const float dxc  = px - ccx;
    const float dyc  = py - ccy;

    const int wbase = ix * LDSP + wv * 8;   // this thread's LDS slot base (per channel)

    #pragma unroll
    for (int j = 0; j < 8; ++j) {
        const float pz = (j < 4) ? pza[j] : pzb[j - 4];

        const float h0 = h0xy + m02 * pz;
        const float h1 = h1xy + m12 * pz;
        const float h2 = h2xy + m22 * pz;

        const float depth = h2;
        const float safe  = (fabsf(depth) > 1e-8f) ? depth : 1e-8f;
        const float u = h0 / safe;
        const float v = h1 / safe;

        const float valid = (depth > 0.0f && u >= 0.0f && u <= (float)(Wc - 1) &&
                             v >= 0.0f && v <= (float)(Hc - 1)) ? 1.0f : 0.0f;

        const float x0f = floorf(u);
        const float y0f = floorf(v);
        const float wx  = u - x0f;
        const float wy  = v - y0f;
        const int   x0  = (int)x0f;
        const int   y0  = (int)y0f;
        const int   x1  = x0 + 1;
        const int   y1  = y0 + 1;

        const float w00 = (1.0f - wx) * (1.0f - wy);
        const float w10 = wx * (1.0f - wy);
        const float w01 = (1.0f - wx) * wy;
        const float w11 = wx * wy;

        const bool ibx0 = (x0 >= 0) & (x0 < Wc);
        const bool ibx1 = (x1 >= 0) & (x1 < Wc);
        const bool iby0 = (y0 >= 0) & (y0 < Hc);
        const bool iby1 = (y1 >= 0) & (y1 < Hc);

        const int cx0 = min(max(x0, 0), Wc - 1);
        const int cx1 = min(max(x1, 0), Wc - 1);
        const int cy0 = min(max(y0, 0), Hc - 1);
        const int cy1 = min(max(y1, 0), Hc - 1);

        // corner-pair base: pair[0]=img[xb], pair[1]=img[xb+1]; cx0,cx1 in {xb,xb+1}
        const int  xb   = min(cx0, Wc - 2);
        const bool s0   = (cx0 != xb);
        const bool s1   = (cx1 != xb);
        const int  row0 = cy0 * Wc + xb;
        const int  row1 = cy1 * Wc + xb;

        #pragma unroll
        for (int c = 0; c < Cc; ++c) {
            const float* __restrict__ img = images + img_base + (size_t)c * (Hc * Wc);
            const f32x2_a4 p0 = *reinterpret_cast<const f32x2_a4*>(img + row0);
            const f32x2_a4 p1 = *reinterpret_cast<const f32x2_a4*>(img + row1);
            const float v00 = (ibx0 & iby0) ? (s0 ? p0.y : p0.x) : 0.0f;
            const float v10 = (ibx1 & iby0) ? (s1 ? p0.y : p0.x) : 0.0f;
            const float v01 = (ibx0 & iby1) ? (s0 ? p1.y : p1.x) : 0.0f;
            const float v11 = (ibx1 & iby1) ? (s1 ? p1.y : p1.x) : 0.0f;
            lds[c * CHSZ + wbase + j] = v00 * w00 + v10 * w10 + v01 * w01 + v11 * w11;
        }

        lds[3 * CHSZ + wbase + j] = depth;
        lds[4 * CHSZ + wbase + j] = valid;

        const float dz  = pz - ccz;
        const float nrm = sqrtf(dxc * dxc + dyc * dyc + dz * dz);
        const float inv = 1.0f / fmaxf(nrm, 1e-8f);
        lds[5 * CHSZ + wbase + j] = dxc * inv;
        lds[6 * CHSZ + wbase + j] = dyc * inv;
        lds[7 * CHSZ + wbase + j] = dz * inv;
    }

    __syncthreads();   // the ONLY barrier

    // ---- store phase: barrier-free; wave = two full 128B runs per instr, NT ----
    float* __restrict__ op = out + (size_t)bip * CHo * Nc + iy * 64 + izc * 32;
    const int izs = ix & 31;
    #pragma unroll
    for (int ch = 0; ch < CHo; ++ch) {
        #pragma unroll
        for (int s = 0; s < 8; ++s) {
            const int ixs = wv * 16 + s * 2 + (ix >> 5);
            __builtin_nontemporal_store(lds[ch * CHSZ + ixs * LDSP + izs],
                                        op + (size_t)ch * Nc + ixs * 4096 + izs);
        }
    }
}

extern "C" void kernel_launch(void* const* d_in, const int* in_sizes, int n_in,
                              void* d_out, int out_size, void* d_ws, size_t ws_size,
                              hipStream_t stream) {
    const float* images = (const float*)d_in[0];
    const float* trans  = (const float*)d_in[1];
    const float* tcw    = (const float*)d_in[2];
    const float* coords = (const float*)d_in[3];
    float* out = (float*)d_out;

    dim3 grid(Bc * IPc, 128);   // camera fastest: linear id = bip + 8*gx -> XCD = bip
    dim3 block(256);
    smear_images_kernel<<<grid, block, 0, stream>>>(images, trans, tcw, coords, out);
}